// Round 4
// baseline (209.732 us; speedup 1.0000x reference)
//
#include <hip/hip_runtime.h>
#include <hip/hip_bf16.h>

// CAM: per batch b (B=16):  a = x[b] viewed as [N=4096, C=256]
//   aTa  = a^T a            [C, C]
//   attn = softmax(aTa, -1)
//   y    = a · attn         [N, C]
//   out  = gamma * y + x
// Storage: fp32 (values bf16-quantized by harness). Internal: bf16 MFMA, fp32 accum.
//
// R3->R4: R3 never ran (container died twice). Audit found a REAL hazard in
// R3's lds_barrier(): __builtin_amdgcn_s_barrier() is compiler-"nomem" —
// LDS ops can be moved across it; only the waitcnt asm had the "memory"
// clobber, so a post-barrier ds_read could hoist between waitcnt and
// s_barrier => race on the LDS tile. Fix: ONE asm volatile containing
// `s_waitcnt lgkmcnt(0); s_barrier` with "memory" clobber covering both.
// Everything else byte-identical to R3:
//   - raw barriers that do NOT drain vmcnt (the __syncthreads lowering
//     `s_waitcnt vmcnt(0)` was draining the prefetch every K-step in R1/R2)
//   - gemm1: 2-deep register prefetch (pfA/pfB named, rule #20)
//   - gemm2: 1-deep issue-early prefetch
// Swizzle proof note (gamma==0 blinds the harness to gemm1 errors): wave w
// writes short8v at logical chunk 8w, slot s holds n=(s>>3)+8*(s&7); XOR key
// (c>>2)&7 on 8-slot chunks cancels between write and read per-row, so the
// effective k-permutation is row-independent and identical for A/B fragments.

#define BB 16
#define NN 4096   // H*W
#define CC 256
#define SPLITK 8
#define KCHUNK (NN / SPLITK)   // 512

typedef __attribute__((ext_vector_type(4))) short short4v;
typedef __attribute__((ext_vector_type(8))) short short8v;
typedef __attribute__((ext_vector_type(4))) float floatx4;

__device__ __forceinline__ unsigned short f2bf(float f) {
    unsigned int u = __float_as_uint(f);
    u += 0x7fffu + ((u >> 16) & 1u);   // RNE (exact for already-bf16-grid values)
    return (unsigned short)(u >> 16);
}
__device__ __forceinline__ short4v cvt4(floatx4 v) {
    short4v r;
    r[0] = (short)f2bf(v[0]); r[1] = (short)f2bf(v[1]);
    r[2] = (short)f2bf(v[2]); r[3] = (short)f2bf(v[3]);
    return r;
}
// LDS-ordering barrier: waits own LDS ops + syncs waves, does NOT drain vmcnt.
// Single asm block so the "memory" clobber fences BOTH instructions — the
// bare s_barrier builtin is "nomem" and the compiler may move LDS ops past it.
__device__ __forceinline__ void lds_barrier() {
    asm volatile("s_waitcnt lgkmcnt(0)\n\ts_barrier" ::: "memory");
}

// ---------------- K1: part[split][b] = partial a^T a (fused transpose) ----
// grid (SPLITK, BB, 2) = 256 blocks, 512 threads (8 waves), 2 waves/SIMD.
// 2-deep register prefetch: pf issued for k0+128 right after consumption,
// lands ~2 full K-step bodies later.
__global__ __launch_bounds__(512, 2) void k_gemm1(const float* __restrict__ x,
                                                  float* __restrict__ part) {
    __shared__ unsigned short P[256 * 72];   // [c][64 slots + pad], 36.9 KB
    const int split = blockIdx.x;
    const int b     = blockIdx.y;
    const int half  = blockIdx.z;
    const int t  = threadIdx.x;
    const int w  = t >> 6, l = t & 63;
    const int lk = (l >> 4) * 8;
    const int lm = l & 15;
    const int i0 = half * 128;
    const int wr = (w >> 2) * 64;            // wave tile 64 x 64
    const int wc = (w & 3) * 64;
    const unsigned swz = (unsigned)(l & 7) << 3;   // == ((c>>2)&7)<<3 for c=4l+j

    const float* xb = x + ((size_t)b * NN + (size_t)split * KCHUNK) * CC + 4 * l;

    floatx4 acc[4][4] = {};

    auto LOADP = [&](floatx4 (&pf)[8], int k0) {
        const float* xn = xb + (size_t)k0 * CC;
        #pragma unroll
        for (int p = 0; p < 8; ++p)
            pf[p] = *(const floatx4*)(xn + (size_t)(w + 8 * p) * CC);   // n = k0 + w + 8p
    };
    auto STEP = [&](floatx4 (&pf)[8], int k0) {
        // consume prefetched rows (compiler inserts counted vmcnt waits here)
        short4v s[8];
        #pragma unroll
        for (int p = 0; p < 8; ++p) s[p] = cvt4(pf[p]);
        // issue 2-ahead into the freed buffer — stays in flight across barriers
        if (k0 + 128 < KCHUNK) LOADP(pf, k0 + 128);
        #pragma unroll
        for (int j = 0; j < 4; ++j) {
            short8v o;
            #pragma unroll
            for (int e = 0; e < 8; ++e) o[e] = s[e][j];   // n = w + 8e
            const unsigned c = (unsigned)(4 * l + j);
            *(short8v*)&P[c * 72 + (((unsigned)(8 * w)) ^ swz)] = o;
        }
        lds_barrier();                 // writes visible; vmcnt NOT drained
        #pragma unroll
        for (int ks = 0; ks < 64; ks += 32) {
            short8v af[4], bf[4];
            #pragma unroll
            for (int mt = 0; mt < 4; ++mt) {
                const unsigned row = (unsigned)(i0 + wr + mt * 16 + lm);
                af[mt] = *(const short8v*)&P[row * 72 + (((unsigned)(ks + lk)) ^ (((row >> 2) & 7u) << 3))];
            }
            #pragma unroll
            for (int nt = 0; nt < 4; ++nt) {
                const unsigned row = (unsigned)(wc + nt * 16 + lm);
                bf[nt] = *(const short8v*)&P[row * 72 + (((unsigned)(ks + lk)) ^ (((row >> 2) & 7u) << 3))];
            }
            #pragma unroll
            for (int mt = 0; mt < 4; ++mt)
                #pragma unroll
                for (int nt = 0; nt < 4; ++nt)
                    acc[mt][nt] = __builtin_amdgcn_mfma_f32_16x16x32_bf16(af[mt], bf[nt], acc[mt][nt], 0, 0, 0);
        }
        lds_barrier();                 // reads retired; safe to overwrite LDS
    };

    floatx4 pfA[8], pfB[8];
    LOADP(pfA, 0);
    LOADP(pfB, 64);
    #pragma unroll
    for (int k0 = 0; k0 < KCHUNK; k0 += 128) {
        STEP(pfA, k0);
        STEP(pfB, k0 + 64);
    }

    const int orow = (l >> 4) * 4;    // C/D: row=(lane>>4)*4+r, col=lane&15
    float* pout = part + (size_t)(split * BB + b) * CC * CC;
    #pragma unroll
    for (int mt = 0; mt < 4; ++mt)
        #pragma unroll
        for (int nt = 0; nt < 4; ++nt)
            #pragma unroll
            for (int r = 0; r < 4; ++r) {
                int i = i0 + wr + mt * 16 + orow + r;
                int j = wc + nt * 16 + lm;
                pout[(size_t)i * CC + j] = acc[mt][nt][r];
            }
}

// ---------------- K2: attn_T[b][j][i] = softmax over summed partials ----
__global__ __launch_bounds__(256) void k_softmax(const float* __restrict__ part,
                                                 unsigned short* __restrict__ attnT) {
    const int w = threadIdx.x >> 6;
    const int l = threadIdx.x & 63;
    const int row = blockIdx.x * 4 + w;   // 0..B*C-1
    const int b = row >> 8;
    const int i = row & 255;
    float v0 = 0.f, v1 = 0.f, v2 = 0.f, v3 = 0.f;
    #pragma unroll
    for (int s = 0; s < SPLITK; ++s) {
        const float* p = part + ((size_t)(s * BB + b) * CC + i) * CC;
        v0 += p[l]; v1 += p[l + 64]; v2 += p[l + 128]; v3 += p[l + 192];
    }
    float m = fmaxf(fmaxf(v0, v1), fmaxf(v2, v3));
    for (int off = 32; off >= 1; off >>= 1) m = fmaxf(m, __shfl_xor(m, off, 64));
    v0 = __expf(v0 - m); v1 = __expf(v1 - m); v2 = __expf(v2 - m); v3 = __expf(v3 - m);
    float s = v0 + v1 + v2 + v3;
    for (int off = 32; off >= 1; off >>= 1) s += __shfl_xor(s, off, 64);
    float rs = 1.0f / s;
    unsigned short* o = attnT + (size_t)b * CC * CC + i;   // attnT[b][j][i]
    o[(size_t)(l +   0) * CC] = f2bf(v0 * rs);
    o[(size_t)(l +  64) * CC] = f2bf(v1 * rs);
    o[(size_t)(l + 128) * CC] = f2bf(v2 * rs);
    o[(size_t)(l + 192) * CC] = f2bf(v3 * rs);
}

// ---------------- K3: out = gamma * (a · attn) + x ----------------------
// Block tile: 64 n-rows x ALL 256 j. grid (64, BB) = 1024 blocks.
// 1-deep issue-early prefetch + raw barriers (no vmcnt drain in loop).
__global__ __launch_bounds__(256, 3) void k_gemm2(const float* __restrict__ x,
                                                  const unsigned short* __restrict__ attnT,
                                                  const float* __restrict__ gamma,
                                                  float* __restrict__ out) {
    __shared__ unsigned short At[64 * 72];    // [n_local][k]
    __shared__ unsigned short Bt[256 * 72];   // [j][k]
    const int n0 = blockIdx.x * 64;
    const int b  = blockIdx.y;
    const int t  = threadIdx.x;
    const int w  = t >> 6, l = t & 63;
    const int lk = (l >> 4) * 8, lm = l & 15;
    const int sc = t >> 4, sk = (t & 15) * 4;

    const float*          Abase = x + ((size_t)b * NN + n0) * CC;
    const unsigned short* Bbase = attnT + (size_t)b * CC * CC;

    floatx4 pA[4];
    short4v pB[16];
    auto LOADA = [&](int k0) {
        #pragma unroll
        for (int r = 0; r < 4; ++r)
            pA[r] = *(const floatx4*)(Abase + (size_t)(sc + 16 * r) * CC + k0 + sk);
    };
    auto LOADB = [&](int k0) {
        #pragma unroll
        for (int r = 0; r < 16; ++r)
            pB[r] = *(const short4v*)(Bbase + (size_t)(sc + 16 * r) * CC + k0 + sk);
    };

    floatx4 acc[4][4] = {};
    LOADA(0); LOADB(0);
    #pragma unroll
    for (int k0 = 0; k0 < CC; k0 += 64) {
        #pragma unroll
        for (int r = 0; r < 4; ++r)
            *(short4v*)&At[(sc + 16 * r) * 72 + sk] = cvt4(pA[r]);
        #pragma unroll
        for (int r = 0; r < 16; ++r)
            *(short4v*)&Bt[(sc + 16 * r) * 72 + sk] = pB[r];
        // issue next k-tile NOW — lands during MFMA phase + barriers
        if (k0 + 64 < CC) { LOADA(k0 + 64); LOADB(k0 + 64); }
        lds_barrier();
        #pragma unroll
        for (int ks = 0; ks < 64; ks += 32) {
            short8v af[4], bf[4];
            #pragma unroll
            for (int mt = 0; mt < 4; ++mt)
                af[mt] = *(const short8v*)&At[(mt * 16 + lm) * 72 + ks + lk];
            #pragma unroll
            for (int nt = 0; nt < 4; ++nt)
                bf[nt] = *(const short8v*)&Bt[(w * 64 + nt * 16 + lm) * 72 + ks + lk];
            #pragma unroll
            for (int mt = 0; mt < 4; ++mt)
                #pragma unroll
                for (int nt = 0; nt < 4; ++nt)
                    acc[mt][nt] = __builtin_amdgcn_mfma_f32_16x16x32_bf16(af[mt], bf[nt], acc[mt][nt], 0, 0, 0);
        }
        lds_barrier();
    }
    const float g = gamma[0];
    const int orow = (l >> 4) * 4;
    #pragma unroll
    for (int mt = 0; mt < 4; ++mt)
        #pragma unroll
        for (int nt = 0; nt < 4; ++nt)
            #pragma unroll
            for (int r = 0; r < 4; ++r) {
                int nr = n0 + mt * 16 + orow + r;
                int j  = w * 64 + nt * 16 + lm;
                size_t idx = ((size_t)b * NN + nr) * CC + j;
                out[idx] = g * acc[mt][nt][r] + x[idx];
            }
}

extern "C" void kernel_launch(void* const* d_in, const int* in_sizes, int n_in,
                              void* d_out, int out_size, void* d_ws, size_t ws_size,
                              hipStream_t stream) {
    const float* x     = (const float*)d_in[0];
    const float* gamma = (const float*)d_in[1];
    float* out = (float*)d_out;

    char* ws = (char*)d_ws;
    float*          part  = (float*)ws;                                   // 8*16*256*256*4 = 32 MB
    unsigned short* attnT = (unsigned short*)(ws + (size_t)SPLITK * BB * CC * CC * 4);  // 2 MB

    k_gemm1  <<<dim3(SPLITK, BB, 2),  512, 0, stream>>>(x, part);
    k_softmax<<<dim3(BB * CC / 4),    256, 0, stream>>>(part, attnT);
    k_gemm2  <<<dim3(NN / 64, BB),    256, 0, stream>>>(x, attnT, gamma, out);
}

// Round 5
// 165.674 us; speedup vs baseline: 1.2659x; 1.2659x over previous
//
#include <hip/hip_runtime.h>
#include <hip/hip_bf16.h>

// CAM: per batch b (B=16):  a = x[b] viewed as [N=4096, C=256]
//   aTa  = a^T a            [C, C]
//   attn = softmax(aTa, -1)
//   y    = a · attn         [N, C]
//   out  = gamma * y + x
// Storage: fp32 (values bf16-quantized by harness). Internal: bf16 MFMA, fp32 accum.
//
// R4->R5: R4's per-kernel counters showed k_gemm2 = 86.6us with EVERYTHING
// idle (MfmaUtil 3.6%, HBM 37%, Occ 21%) — latency-bound 2-barrier k-loop
// with only 4 K-steps, plus 2.25x write amplification from scalar stores.
// The raw-asm-barrier experiment (R4) regressed 50us total -> reverted
// everywhere. New k_gemm2: BARRIER-FREE k-loop —
//   * stage full 64x256 A-panel once (32KB LDS, stride 260 shorts), ONE
//     __syncthreads in the whole kernel;
//   * B fragments read DIRECTLY from global attnT (16B contiguous per lane;
//     each block reads attnT[b]=128KB exactly once, L2-resident across the
//     64 blocks/batch);
//   * grid 1024 = exactly 4 blocks/CU (LDS 33KB) x 256 CUs, 16 waves/CU TLP;
//   * epilogue: in-register 4x4 shfl-xor transpose -> float4 loads of x and
//     float4 stores of out (fp32 x read — no bf16-grid assumption).
// k_gemm1 reverted to the exact R2 version (__syncthreads, 8 waves).

#define BB 16
#define NN 4096   // H*W
#define CC 256
#define SPLITK 8
#define KCHUNK (NN / SPLITK)   // 512

typedef __attribute__((ext_vector_type(4))) short short4v;
typedef __attribute__((ext_vector_type(8))) short short8v;
typedef __attribute__((ext_vector_type(4))) float floatx4;

__device__ __forceinline__ unsigned short f2bf(float f) {
    unsigned int u = __float_as_uint(f);
    u += 0x7fffu + ((u >> 16) & 1u);   // RNE (exact for already-bf16-grid values)
    return (unsigned short)(u >> 16);
}
__device__ __forceinline__ short4v cvt4(floatx4 v) {
    short4v r;
    r[0] = (short)f2bf(v[0]); r[1] = (short)f2bf(v[1]);
    r[2] = (short)f2bf(v[2]); r[3] = (short)f2bf(v[3]);
    return r;
}

// ---------------- K1: part[split][b] = partial a^T a (fused transpose) ----
// grid (SPLITK, BB, 2) = 256 blocks, 512 threads (8 waves), 2 waves/SIMD.
// (Exact R2 version — known-good inside the 159.8us total.)
__global__ __launch_bounds__(512, 2) void k_gemm1(const float* __restrict__ x,
                                                  float* __restrict__ part) {
    __shared__ unsigned short P[256 * 72];   // [c][64 slots + pad], 36.9 KB
    const int split = blockIdx.x;
    const int b     = blockIdx.y;
    const int half  = blockIdx.z;
    const int t  = threadIdx.x;
    const int w  = t >> 6, l = t & 63;
    const int lk = (l >> 4) * 8;
    const int lm = l & 15;
    const int i0 = half * 128;
    const int wr = (w >> 2) * 64;            // wave tile 64 x 64
    const int wc = (w & 3) * 64;
    const unsigned swz = (unsigned)(l & 7) << 3;   // == ((c>>2)&7)<<3 for c=4l+j

    const float* xb = x + ((size_t)b * NN + (size_t)split * KCHUNK) * CC + 4 * l;

    floatx4 pf[8];
    #pragma unroll
    for (int p = 0; p < 8; ++p)
        pf[p] = *(const floatx4*)(xb + (size_t)(w + 8 * p) * CC);   // n = w + 8p

    floatx4 acc[4][4] = {};

    for (int k0 = 0; k0 < KCHUNK; k0 += 64) {
        // bf16 convert + in-register 8x4 -> 4x8 transpose
        short4v s[8];
        #pragma unroll
        for (int p = 0; p < 8; ++p) s[p] = cvt4(pf[p]);
        #pragma unroll
        for (int j = 0; j < 4; ++j) {
            short8v o;
            #pragma unroll
            for (int e = 0; e < 8; ++e) o[e] = s[e][j];   // n = w + 8e
            const unsigned c = (unsigned)(4 * l + j);
            *(short8v*)&P[c * 72 + (((unsigned)(8 * w)) ^ swz)] = o;
        }
        __syncthreads();
        // prefetch next 64-n chunk
        if (k0 + 64 < KCHUNK) {
            const float* xn = xb + (size_t)(k0 + 64) * CC;
            #pragma unroll
            for (int p = 0; p < 8; ++p)
                pf[p] = *(const floatx4*)(xn + (size_t)(w + 8 * p) * CC);
        }
        #pragma unroll
        for (int ks = 0; ks < 64; ks += 32) {
            short8v af[4], bf[4];
            #pragma unroll
            for (int mt = 0; mt < 4; ++mt) {
                const unsigned row = (unsigned)(i0 + wr + mt * 16 + lm);
                af[mt] = *(const short8v*)&P[row * 72 + (((unsigned)(ks + lk)) ^ (((row >> 2) & 7u) << 3))];
            }
            #pragma unroll
            for (int nt = 0; nt < 4; ++nt) {
                const unsigned row = (unsigned)(wc + nt * 16 + lm);
                bf[nt] = *(const short8v*)&P[row * 72 + (((unsigned)(ks + lk)) ^ (((row >> 2) & 7u) << 3))];
            }
            #pragma unroll
            for (int mt = 0; mt < 4; ++mt)
                #pragma unroll
                for (int nt = 0; nt < 4; ++nt)
                    acc[mt][nt] = __builtin_amdgcn_mfma_f32_16x16x32_bf16(af[mt], bf[nt], acc[mt][nt], 0, 0, 0);
        }
        __syncthreads();
    }
    const int orow = (l >> 4) * 4;    // C/D: row=(lane>>4)*4+r, col=lane&15
    float* pout = part + (size_t)(split * BB + b) * CC * CC;
    #pragma unroll
    for (int mt = 0; mt < 4; ++mt)
        #pragma unroll
        for (int nt = 0; nt < 4; ++nt)
            #pragma unroll
            for (int r = 0; r < 4; ++r) {
                int i = i0 + wr + mt * 16 + orow + r;
                int j = wc + nt * 16 + lm;
                pout[(size_t)i * CC + j] = acc[mt][nt][r];
            }
}

// ---------------- K2: attn_T[b][j][i] = softmax over summed partials ----
__global__ __launch_bounds__(256) void k_softmax(const float* __restrict__ part,
                                                 unsigned short* __restrict__ attnT) {
    const int w = threadIdx.x >> 6;
    const int l = threadIdx.x & 63;
    const int row = blockIdx.x * 4 + w;   // 0..B*C-1
    const int b = row >> 8;
    const int i = row & 255;
    float v0 = 0.f, v1 = 0.f, v2 = 0.f, v3 = 0.f;
    #pragma unroll
    for (int s = 0; s < SPLITK; ++s) {
        const float* p = part + ((size_t)(s * BB + b) * CC + i) * CC;
        v0 += p[l]; v1 += p[l + 64]; v2 += p[l + 128]; v3 += p[l + 192];
    }
    float m = fmaxf(fmaxf(v0, v1), fmaxf(v2, v3));
    for (int off = 32; off >= 1; off >>= 1) m = fmaxf(m, __shfl_xor(m, off, 64));
    v0 = __expf(v0 - m); v1 = __expf(v1 - m); v2 = __expf(v2 - m); v3 = __expf(v3 - m);
    float s = v0 + v1 + v2 + v3;
    for (int off = 32; off >= 1; off >>= 1) s += __shfl_xor(s, off, 64);
    float rs = 1.0f / s;
    unsigned short* o = attnT + (size_t)b * CC * CC + i;   // attnT[b][j][i]
    o[(size_t)(l +   0) * CC] = f2bf(v0 * rs);
    o[(size_t)(l +  64) * CC] = f2bf(v1 * rs);
    o[(size_t)(l + 128) * CC] = f2bf(v2 * rs);
    o[(size_t)(l + 192) * CC] = f2bf(v3 * rs);
}

// ---------------- K3: out = gamma * (a · attn) + x ----------------------
// Barrier-free k-loop. grid (64, BB) = 1024 blocks = 4/CU x 256 CUs.
// A-panel (64x256) staged once in LDS; B-frags straight from global (L2-hot);
// epilogue: shfl-transpose -> float4 x-load + float4 out-store.
#define ALD 260   // At row stride in shorts (stride%32dw==2 -> ~2-way banks)
__global__ __launch_bounds__(256, 4) void k_gemm2(const float* __restrict__ x,
                                                  const unsigned short* __restrict__ attnT,
                                                  const float* __restrict__ gamma,
                                                  float* __restrict__ out) {
    __shared__ unsigned short At[64 * ALD];   // 33.3 KB
    const int n0 = blockIdx.x * 64;
    const int b  = blockIdx.y;
    const int t  = threadIdx.x;
    const int w  = t >> 6, l = t & 63;
    const int lk = (l >> 4) * 8, lm = l & 15;

    const float* Abase = x + ((size_t)b * NN + n0) * CC;

    // ---- stage full A-panel (64 rows x 256 ch), fully coalesced ----
    #pragma unroll
    for (int r = 0; r < 16; ++r) {
        int idx = r * 256 + t;            // float4 index in the 64x256 panel
        int row = idx >> 6;
        int col = (idx & 63) * 4;
        floatx4 v = *(const floatx4*)(Abase + (size_t)row * CC + col);
        *(short4v*)&At[row * ALD + col] = cvt4(v);
    }
    __syncthreads();                      // the ONLY barrier

    // ---- barrier-free K-loop: A from LDS, B from global (L2-resident) ----
    const unsigned short* Bb = attnT + (size_t)b * CC * CC;
    floatx4 acc[4][4] = {};
    #pragma unroll
    for (int k0 = 0; k0 < CC; k0 += 32) {
        short8v af[4], bf[4];
        #pragma unroll
        for (int mt = 0; mt < 4; ++mt)
            af[mt] = *(const short8v*)&At[(mt * 16 + lm) * ALD + k0 + lk];
        #pragma unroll
        for (int nt = 0; nt < 4; ++nt)
            bf[nt] = *(const short8v*)(Bb + (size_t)(w * 64 + nt * 16 + lm) * CC + k0 + lk);
        #pragma unroll
        for (int mt = 0; mt < 4; ++mt)
            #pragma unroll
            for (int nt = 0; nt < 4; ++nt)
                acc[mt][nt] = __builtin_amdgcn_mfma_f32_16x16x32_bf16(af[mt], bf[nt], acc[mt][nt], 0, 0, 0);
    }

    // ---- epilogue: 4x4 shfl-xor transpose -> float4 ----
    // pre: lane holds col lm, rows orow..orow+3. post: row orow+(lm&3),
    // cols (lm&12)..+3.  (exchange verified lane-by-lane.)
    const float g = gamma[0];
    const int orow = (l >> 4) * 4;
    #pragma unroll
    for (int mt = 0; mt < 4; ++mt)
        #pragma unroll
        for (int nt = 0; nt < 4; ++nt) {
            float v0 = acc[mt][nt][0], v1 = acc[mt][nt][1];
            float v2 = acc[mt][nt][2], v3 = acc[mt][nt][3];
            float tt;
            tt = __shfl_xor((lm & 1) ? v0 : v1, 1, 64); if (lm & 1) v0 = tt; else v1 = tt;
            tt = __shfl_xor((lm & 1) ? v2 : v3, 1, 64); if (lm & 1) v2 = tt; else v3 = tt;
            tt = __shfl_xor((lm & 2) ? v0 : v2, 2, 64); if (lm & 2) v0 = tt; else v2 = tt;
            tt = __shfl_xor((lm & 2) ? v1 : v3, 2, 64); if (lm & 2) v1 = tt; else v3 = tt;
            int nr = n0 + mt * 16 + orow + (lm & 3);
            int jc = w * 64 + nt * 16 + (lm & 12);
            size_t ro = ((size_t)b * NN + nr) * CC + jc;
            floatx4 xv = *(const floatx4*)(x + ro);
            floatx4 ov;
            ov[0] = g * v0 + xv[0]; ov[1] = g * v1 + xv[1];
            ov[2] = g * v2 + xv[2]; ov[3] = g * v3 + xv[3];
            *(floatx4*)(out + ro) = ov;
        }
}

extern "C" void kernel_launch(void* const* d_in, const int* in_sizes, int n_in,
                              void* d_out, int out_size, void* d_ws, size_t ws_size,
                              hipStream_t stream) {
    const float* x     = (const float*)d_in[0];
    const float* gamma = (const float*)d_in[1];
    float* out = (float*)d_out;

    char* ws = (char*)d_ws;
    float*          part  = (float*)ws;                                   // 8*16*256*256*4 = 32 MB
    unsigned short* attnT = (unsigned short*)(ws + (size_t)SPLITK * BB * CC * CC * 4);  // 2 MB

    k_gemm1  <<<dim3(SPLITK, BB, 2),  512, 0, stream>>>(x, part);
    k_softmax<<<dim3(BB * CC / 4),    256, 0, stream>>>(part, attnT);
    k_gemm2  <<<dim3(NN / 64, BB),    256, 0, stream>>>(x, attnT, gamma, out);
}